// Round 9
// baseline (119.457 us; speedup 1.0000x reference)
//
#include <hip/hip_runtime.h>

#define B_    32
#define S_    64
#define D_    8
#define NE_   512        // S_*D_
#define E_    150000
#define CAP   448        // compacted edges per bin (mean 293, ~9 sigma headroom)

// scatter: 37 blocks x 1024 threads x 4 edges = 151552 slots >= E_
#define SC_BLK   1024
#define SC_EPT   4
#define SC_EPB   (SC_BLK * SC_EPT)                 // 4096
#define SC_GRID  ((E_ + SC_EPB - 1) / SC_EPB)      // 37
#define SLOTS    32                                 // per (bin,blk); mean 8, +8.5 sigma
#define PITCH    (SC_GRID * SLOTS)                  // 1184 ints per bin

// ws: cnt2D[NE_][SC_GRID] at 0 (76KB) | payload2D[NE_][PITCH] at 128KB (2.4MB)
#define PAYLOAD_BYTE_OFF 131072

typedef __attribute__((ext_vector_type(8)))  short  short8;   // 8 bf16 (4 VGPR)
typedef __attribute__((ext_vector_type(16))) float  float16;  // MFMA C/D (16 regs)

__device__ __forceinline__ unsigned short f2bf(float f) {
    union { float f; unsigned int u; } cv; cv.f = f;
    unsigned int u = cv.u;
    return (unsigned short)((u + 0x7fffu + ((u >> 16) & 1u)) >> 16);
}
__device__ __forceinline__ unsigned int pack2bf(float a, float b) {
    return (unsigned int)f2bf(a) | ((unsigned int)f2bf(b) << 16);
}

// ---------------- init-free binning scatter (no memset, no global atomics) -----
__global__ __launch_bounds__(SC_BLK)
void scatter_bin(const int* __restrict__ inc,
                 int* __restrict__ cnt2D,        // [NE_][SC_GRID]
                 int* __restrict__ payload2D) {  // [NE_][PITCH]
    __shared__ int lcount[NE_];
    const int tid = threadIdx.x;

    if (tid < NE_) lcount[tid] = 0;
    __syncthreads();

    int ei[SC_EPT], lp[SC_EPT], pl[SC_EPT];
    #pragma unroll
    for (int i = 0; i < SC_EPT; ++i) {
        const int e = blockIdx.x * SC_EPB + i * SC_BLK + tid;   // coalesced
        ei[i] = -1;
        if (e < E_) {
            const int4 c = ((const int4*)inc)[e];   // c0=batch c1=node c2 c3
            ei[i] = c.z * D_ + c.w;
            pl[i] = (c.x << 16) | (c.y * S_ + c.z);
            lp[i] = atomicAdd(&lcount[ei[i]], 1);   // LDS atomic only
        }
    }
    #pragma unroll
    for (int i = 0; i < SC_EPT; ++i)
        if (ei[i] >= 0 && lp[i] < SLOTS)
            payload2D[ei[i] * PITCH + blockIdx.x * SLOTS + lp[i]] = pl[i];
    __syncthreads();
    if (tid < NE_)
        cnt2D[tid * SC_GRID + blockIdx.x] = min(lcount[tid], SLOTS);
}

// ---------------- MFMA main kernel: single-phase issue ----------------
// ALL global loads (payload, counts, weights, gathers, staging) are issued
// before the first barrier. Per-wave register scan (no cross-wave scan dep).
// Gathers run on RAW slots (2.3x over-gather, L2/L3-deduped); compaction
// scatters packed bf16 x-fragments into LDS. 3 barriers total.
// NOTE: all __shfl calls execute in CONVERGED code (shfl from an inactive
// source lane is undefined on CDNA — this was round 8's correctness bug).
// C/D layout: col = lane&31, row = (reg&3) + 8*(reg>>2) + 4*(lane>>5)

#define TILE_COMPUTE(bXv, pvv, vldv)                                            \
  {                                                                             \
    float16 c0;                                                                 \
    _Pragma("unroll")                                                           \
    for (int r = 0; r < 16; ++r)                                                \
        c0[r] = bias0s[(r & 3) + 8 * (r >> 2) + 4 * q];                         \
    c0 = __builtin_amdgcn_mfma_f32_32x32x16_bf16(aWa, (bXv), c0, 0, 0, 0);      \
    unsigned Pw[8];                                                             \
    _Pragma("unroll")                                                           \
    for (int j = 0; j < 8; ++j)                                                 \
        Pw[j] = pack2bf(fmaxf(c0[2 * j], 0.f), fmaxf(c0[2 * j + 1], 0.f));      \
    asm("v_permlane32_swap_b32 %0, %1" : "+v"(Pw[0]), "+v"(Pw[2]));             \
    asm("v_permlane32_swap_b32 %0, %1" : "+v"(Pw[1]), "+v"(Pw[3]));             \
    asm("v_permlane32_swap_b32 %0, %1" : "+v"(Pw[4]), "+v"(Pw[6]));             \
    asm("v_permlane32_swap_b32 %0, %1" : "+v"(Pw[5]), "+v"(Pw[7]));             \
    union { unsigned u[4]; short8 s; } H0c, H1c;                                \
    H0c.u[0] = Pw[0]; H0c.u[1] = Pw[1]; H0c.u[2] = Pw[2]; H0c.u[3] = Pw[3];     \
    H1c.u[0] = Pw[4]; H1c.u[1] = Pw[5]; H1c.u[2] = Pw[6]; H1c.u[3] = Pw[7];     \
    float16 c1;                                                                 \
    _Pragma("unroll")                                                           \
    for (int r = 0; r < 16; ++r)                                                \
        c1[r] = bias1s[(r & 3) + 8 * (r >> 2) + 4 * q];                         \
    c1 = __builtin_amdgcn_mfma_f32_32x32x16_bf16(aWb0, H0c.s, c1, 0, 0, 0);     \
    c1 = __builtin_amdgcn_mfma_f32_32x32x16_bf16(aWb1, H1c.s, c1, 0, 0, 0);     \
    if (vldv) {                                                                 \
        const int b_e = ((pvv) >> 16) & 31;                                     \
        _Pragma("unroll")                                                       \
        for (int r = 0; r < 16; ++r)                                            \
            atomicAdd(&acc[b_e][(r & 3) + 8 * (r >> 2) + 4 * q],                \
                      fmaxf(c1[r], 0.f));                                       \
        if (q == 0) atomicAdd(&cnts[b_e], 1.f);                                 \
    }                                                                           \
  }

// gather one nf row (16 f32) and pack to 2x 16B bf16 fragments
#define GATHER_PACK(rowv, LO, HI)                                               \
  {                                                                             \
    const float4* xp = (const float4*)(nf + (size_t)(rowv) * 16);               \
    float4 a0 = xp[0], a1 = xp[1], a2 = xp[2], a3 = xp[3];                      \
    LO.x = pack2bf(a0.x, a0.y); LO.y = pack2bf(a0.z, a0.w);                     \
    LO.z = pack2bf(a1.x, a1.y); LO.w = pack2bf(a1.z, a1.w);                     \
    HI.x = pack2bf(a2.x, a2.y); HI.y = pack2bf(a2.z, a2.w);                     \
    HI.z = pack2bf(a3.x, a3.y); HI.w = pack2bf(a3.z, a3.w);                     \
  }

__global__ __launch_bounds__(512, 4)
void main_mfma(const float* __restrict__ nf,
               const float* __restrict__ iw0, const float* __restrict__ ib0,
               const float* __restrict__ iw1, const float* __restrict__ ib1,
               const float* __restrict__ ow0, const float* __restrict__ ob0,
               const float* __restrict__ ow1, const float* __restrict__ ob1,
               const int* __restrict__ cnt2D, const int* __restrict__ payload2D,
               float* __restrict__ out) {
    const int bid  = blockIdx.x;          // == eidx (bin)
    const int tid  = threadIdx.x;
    const int wav  = tid >> 6;            // 0..7
    const int lane = tid & 63;
    const int e32  = lane & 31;           // edge-in-tile / A-row
    const int q    = lane >> 5;           // k-half selector

    __shared__ uint4 xls0[512];           // packed x k=0..7  (8 KB, 16B rows)
    __shared__ uint4 xls1[512];           // packed x k=8..15 (8 KB)
    __shared__ int   elist[512];          // compacted payloads (2 KB)
    __shared__ float acc[32][33];
    __shared__ float hb[32][33];
    __shared__ float cnts[32];
    __shared__ float q0t[32 * 33];        // [k][o] transposed, pad 33
    __shared__ float q1t[32 * 17];        // [k][o] transposed, pad 17
    __shared__ float qb0s[32], qb1s[16];
    __shared__ float bias0s[32], bias1s[32];

    // ===== everything below issues before the first barrier =====

    // --- payload prefetch: 3 raw slots per thread ---
    const int* Pb = payload2D + (size_t)bid * PITCH;
    const int p0 = tid, p1 = tid + 512, p2 = tid + 1024;
    const int r0 = Pb[p0];
    const int r1 = Pb[p1];
    int r2 = 0;
    if (p2 < PITCH) r2 = Pb[p2];

    // --- per-wave count load + register shuffle scan (no LDS, no barrier) ---
    int v = 0;
    if (lane < SC_GRID) v = cnt2D[bid * SC_GRID + lane];
    int incl = v;
    #pragma unroll
    for (int off = 1; off < 64; off <<= 1) {
        const int t = __shfl_up(incl, off);
        if (lane >= off) incl += t;
    }
    const int excl = incl - v;
    const int n = min(__shfl(incl, SC_GRID - 1), CAP);

    // --- per-lane A-frags (weights, packed bf16) ---
    short8 aWa, aWb0, aWb1;
    {
        const float* wa = iw0 + (size_t)bid * 512 + e32 * 16 + q * 8;
        float4 u0 = ((const float4*)wa)[0], u1 = ((const float4*)wa)[1];
        unsigned int p[4] = { pack2bf(u0.x,u0.y), pack2bf(u0.z,u0.w),
                              pack2bf(u1.x,u1.y), pack2bf(u1.z,u1.w) };
        aWa = *(short8*)p;
    }
    {
        const float* wb = iw1 + (size_t)bid * 1024 + e32 * 32 + q * 8;
        float4 u0 = ((const float4*)wb)[0], u1 = ((const float4*)wb)[1];
        unsigned int p[4] = { pack2bf(u0.x,u0.y), pack2bf(u0.z,u0.w),
                              pack2bf(u1.x,u1.y), pack2bf(u1.z,u1.w) };
        aWb0 = *(short8*)p;
        const float* wb2 = wb + 16;
        float4 u2 = ((const float4*)wb2)[0], u3 = ((const float4*)wb2)[1];
        unsigned int p2k[4] = { pack2bf(u2.x,u2.y), pack2bf(u2.z,u2.w),
                                pack2bf(u3.x,u3.y), pack2bf(u3.z,u3.w) };
        aWb1 = *(short8*)p2k;
    }

    // --- raw-slot gathers (depend only on payload; rows are 16-bit safe) ---
    uint4 g0lo = {}, g0hi = {}, g1lo = {}, g1hi = {}, g2lo = {}, g2hi = {};
    GATHER_PACK(r0 & 0xFFFF, g0lo, g0hi);
    GATHER_PACK(r1 & 0xFFFF, g1lo, g1hi);
    GATHER_PACK(r2 & 0xFFFF, g2lo, g2hi);   // r2==0 when p2>=PITCH: row 0, discarded

    // --- LDS staging (out-weights transposed, biases, acc zero) ---
    for (int i = tid; i < 1024; i += 512) {
        const int o = i >> 5, k = i & 31;
        q0t[k * 33 + o] = ow0[(size_t)bid * 1024 + i];
    }
    { const int o = tid >> 5, k = tid & 31;
      q1t[k * 17 + o] = ow1[(size_t)bid * 512 + tid]; }
    if (tid < 32)       { bias0s[tid] = ib0[bid * 32 + tid]; cnts[tid] = 0.f; }
    else if (tid < 64)  bias1s[tid - 32] = ib1[bid * 32 + (tid - 32)];
    else if (tid < 96)  qb0s[tid - 64] = ob0[bid * 32 + (tid - 64)];
    else if (tid < 112) qb1s[tid - 96] = ob1[bid * 16 + (tid - 96)];
    for (int i = tid; i < 32 * 33; i += 512) ((float*)acc)[i] = 0.f;

    // --- compaction: ALL shuffles hoisted to converged code, then branch ---
    {
        const int blk0 = p0 >> 5,                 sl0 = p0 & 31;
        const int blk1 = p1 >> 5,                 sl1 = p1 & 31;
        const int blk2 = min(p2 >> 5, SC_GRID-1), sl2 = p2 & 31;
        const int c0_ = __shfl(v, blk0),   b0_ = __shfl(excl, blk0);
        const int c1_ = __shfl(v, blk1),   b1_ = __shfl(excl, blk1);
        const int c2_ = __shfl(v, blk2),   b2_ = __shfl(excl, blk2);
        if (sl0 < c0_) {
            const int idx = b0_ + sl0;
            if (idx < CAP) { elist[idx] = r0; xls0[idx] = g0lo; xls1[idx] = g0hi; }
        }
        if (sl1 < c1_) {
            const int idx = b1_ + sl1;
            if (idx < CAP) { elist[idx] = r1; xls0[idx] = g1lo; xls1[idx] = g1hi; }
        }
        if (p2 < PITCH && sl2 < c2_) {
            const int idx = b2_ + sl2;
            if (idx < CAP) { elist[idx] = r2; xls0[idx] = g2lo; xls1[idx] = g2hi; }
        }
    }
    __syncthreads();   // B1: compaction + staging complete

    // --- both tiles: B-frags straight from LDS; garbage beyond n is masked ---
    const int s0 = (wav << 5) + e32;      // < 256
    const int s1 = s0 + 256;              // < 512
    const int pv0 = elist[s0];
    const int pv1 = elist[s1];
    const bool v0 = s0 < n;
    const bool v1 = s1 < n;
    const short8 bX0 = *(const short8*)(q ? &xls1[s0] : &xls0[s0]);
    const short8 bX1 = *(const short8*)(q ? &xls1[s1] : &xls0[s1]);

    TILE_COMPUTE(bX0, pv0, v0);
    TILE_COMPUTE(bX1, pv1, v1);
    __syncthreads();   // B2: acc/cnts complete

    // --- mean + out layer 0 + out layer 1 (hb reuse is same-wave, in-order) ---
    {
        const int b  = tid >> 4;
        const int j  = tid & 15;
        const float cv  = cnts[b];
        const float inv = cv > 0.f ? 1.0f / cv : 0.0f;
        #pragma unroll
        for (int s = 0; s < 2; ++s) {
            const int oo = j * 2 + s;
            float d = 0.f;
            #pragma unroll
            for (int k = 0; k < 32; ++k) d = fmaf(q0t[k * 33 + oo], acc[b][k], d);
            hb[b][oo] = fmaxf(fmaf(d, inv, qb0s[oo]), 0.f);
        }
        // the 16 threads of group b are within one wave: LDS same-wave ordering
        float d1 = qb1s[j];
        #pragma unroll
        for (int k = 0; k < 32; ++k) d1 = fmaf(q1t[k * 17 + j], hb[b][k], d1);
        out[((size_t)b * NE_ + bid) * 16 + j] = fmaxf(d1, 0.f);
    }
}

extern "C" void kernel_launch(void* const* d_in, const int* in_sizes, int n_in,
                              void* d_out, int out_size, void* d_ws, size_t ws_size,
                              hipStream_t stream) {
    const float* nf  = (const float*)d_in[0];
    const float* iw0 = (const float*)d_in[1];
    const float* ib0 = (const float*)d_in[2];
    const float* iw1 = (const float*)d_in[3];
    const float* ib1 = (const float*)d_in[4];
    const float* ow0 = (const float*)d_in[5];
    const float* ob0 = (const float*)d_in[6];
    const float* ow1 = (const float*)d_in[7];
    const float* ob1 = (const float*)d_in[8];
    const int*   inc = (const int*)d_in[9];

    int* cnt2D     = (int*)d_ws;
    int* payload2D = (int*)((char*)d_ws + PAYLOAD_BYTE_OFF);

    scatter_bin<<<SC_GRID, SC_BLK, 0, stream>>>(inc, cnt2D, payload2D);
    main_mfma<<<NE_, 512, 0, stream>>>(nf, iw0, ib0, iw1, ib1, ow0, ob0, ow1, ob1,
                                       cnt2D, payload2D, (float*)d_out);
}